// Round 1
// 136.995 us; speedup vs baseline: 1.0539x; 1.0539x over previous
//
#include <hip/hip_runtime.h>

// LinearPositionInterpolation: out[b, p-1, :] = lerp(value[b, seg, :], value[b, seg+1, :], w)
// seg = searchsorted(index - index[0], p, 'left') - 1, p in [1, m], m = index[n-1]-index[0].
//
// R1 restructure: one block per (batch, segment). No per-thread search — seg is
// blockIdx. Each lane loads its float4 of y0/y1 ONCE, then streams the segment's
// output rows (w varies, data reused). 134 MB out + 4.2 MB in -> ~22 us floor at 6.3 TB/s.
//
// R3 (this round): the poison fill hits 6.4 TB/s on this very buffer with PLAIN
// cached stores; our nontemporal (nt/sc-bit, L2-bypass) stores sustained only
// ~2.2 TB/s. Drop NT -> regular global_store_dwordx4 through L2, and give each
// wave a CONTIGUOUS row range (linear 8 KB stream per wave, same character as
// the fill) instead of the stride-4 row interleave.

#define DIM 256
#define VEC_PER_ROW (DIM / 4)   // 64 float4 per row == 1 wave per row

typedef float vfloat4 __attribute__((ext_vector_type(4)));

__global__ __launch_bounds__(256) void lpi_kernel(
    const int* __restrict__ index,
    const float* __restrict__ value,
    float* __restrict__ out,
    int n, int m)
{
    int nseg = n - 1;
    int seg  = blockIdx.x % nseg;        // segment id (wave-uniform, scalar)
    int b    = blockIdx.x / nseg;        // batch id

    int base = index[0];
    int x0   = index[seg]     - base;    // tiny, L2-cached
    int x1   = index[seg + 1] - base;
    int len  = x1 - x0;                  // positions in this segment

    int lane = threadIdx.x & 63;         // float4 index within the 256-wide row
    int wv   = threadIdx.x >> 6;         // wave id within block (0..3)

    const vfloat4* y0 = (const vfloat4*)(value + (size_t)(b * n + seg) * DIM);

    vfloat4 a = y0[lane];                // row seg
    vfloat4 c = y0[lane + VEC_PER_ROW];  // row seg+1 (contiguous after row seg)
    vfloat4 d = c - a;                   // diff = y1 - y0, computed once

    float flen = (float)len;

    // Contiguous partition of the segment's rows across the 4 waves:
    // wave wv owns rows k in [len*wv/4, len*(wv+1)/4)  (exact cover, no overlap).
    int lo = (len * wv)       >> 2;
    int hi = (len * (wv + 1)) >> 2;

    vfloat4* op = (vfloat4*)(out + (size_t)(b * m + x0 + lo) * DIM) + lane;
    for (int k = lo; k < hi; ++k) {
        float w = (float)(k + 1) / flen; // == (p - x0)/(x1 - x0), same math as ref
        *op = a + d * w;                 // plain cached store (dwordx4 via L2)
        op += VEC_PER_ROW;
    }
}

extern "C" void kernel_launch(void* const* d_in, const int* in_sizes, int n_in,
                              void* d_out, int out_size, void* d_ws, size_t ws_size,
                              hipStream_t stream) {
    const int*   index = (const int*)d_in[0];
    const float* value = (const float*)d_in[1];
    float*       out   = (float*)d_out;

    int n  = in_sizes[0];                 // 129
    int bd = in_sizes[1] / n;             // batch * dim = 8192
    const int dim = DIM;                  // 256 (per reference setup)
    int batch = bd / dim;                 // 32
    int m = out_size / bd;                // 4096

    int grid = batch * (n - 1);           // 4096 blocks: one per (batch, segment)
    lpi_kernel<<<grid, 256, 0, stream>>>(index, value, out, n, m);
}

// Round 2
// 136.555 us; speedup vs baseline: 1.0573x; 1.0032x over previous
//
#include <hip/hip_runtime.h>

// LinearPositionInterpolation: out[b, p-1, :] = lerp(value[b, seg, :], value[b, seg+1, :], w)
// seg = searchsorted(index - index[0], p, 'left') - 1, p in [1, m], m = index[n-1]-index[0].
//
// R1: one block per (batch, segment); y0/y1 register-cached; pure streaming stores.
// R3: plain cached stores (NT was ~neutral); contiguous per-wave row ranges.
// R4 (this round): kill per-block startup/drain costs.
//   - grid (nseg, batch/2): 2048 blocks = exactly 8 blocks/CU resident (full
//     32-wave occupancy, single dispatch wavefront). Each block does the SAME
//     segment for two batches: index/x0/len loaded once, no div/mod.
//   - ALL value-row loads issued up front (4 KB), one vmcnt wait, then a
//     store-only loop: no load ever queues behind the store stream (vmcnt
//     counts loads AND stores on gfx9 -> mixing forces drains).
//   - two interleaved 1 KB store streams per wave (b0,b1) -> 2x store MLP.
//   - division hoisted: w = (k+1) * (1/len), one divide per block.

#define DIM 256
#define VEC_PER_ROW (DIM / 4)   // 64 float4 per row == 1 wave per row

typedef float vfloat4 __attribute__((ext_vector_type(4)));

__global__ __launch_bounds__(256) void lpi_kernel(
    const int* __restrict__ index,
    const float* __restrict__ value,
    float* __restrict__ out,
    int n, int m, int batch)
{
    int seg = blockIdx.x;                // segment id (wave-uniform, scalar)
    int b0  = blockIdx.y * 2;            // first batch of the pair
    int b1  = b0 + 1;                    // second batch (guarded if batch odd)
    bool has1 = (b1 < batch);

    int base = index[0];
    int x0   = index[seg]     - base;    // tiny, L2-cached
    int x1   = index[seg + 1] - base;
    int len  = x1 - x0;                  // positions in this segment

    int lane = threadIdx.x & 63;         // float4 index within the 256-wide row
    int wv   = threadIdx.x >> 6;         // wave id within block (0..3)

    // Issue all four row-loads up front; single waitcnt covers them.
    const vfloat4* y0a = (const vfloat4*)(value + (size_t)(b0 * n + seg) * DIM);
    const vfloat4* y0b = (const vfloat4*)(value + (size_t)((has1 ? b1 : b0) * n + seg) * DIM);
    vfloat4 a0 = y0a[lane];
    vfloat4 c0 = y0a[lane + VEC_PER_ROW];
    vfloat4 a1 = y0b[lane];
    vfloat4 c1 = y0b[lane + VEC_PER_ROW];

    vfloat4 d0 = c0 - a0;
    vfloat4 d1 = c1 - a1;

    float winc = 1.0f / (float)len;      // hoisted; per-row w = (k+1)*winc

    // Contiguous partition of the segment's rows across the 4 waves.
    int lo = (len * wv)       >> 2;
    int hi = (len * (wv + 1)) >> 2;

    vfloat4* op0 = (vfloat4*)(out + (size_t)(b0 * m + x0 + lo) * DIM) + lane;
    vfloat4* op1 = (vfloat4*)(out + (size_t)(b1 * m + x0 + lo) * DIM) + lane;

    for (int k = lo; k < hi; ++k) {
        float w = (float)(k + 1) * winc;
        *op0 = a0 + d0 * w;              // stream 0: batch b0
        op0 += VEC_PER_ROW;
        if (has1) {                      // wave-uniform branch (scalar)
            *op1 = a1 + d1 * w;          // stream 1: batch b1
        }
        op1 += VEC_PER_ROW;
    }
}

extern "C" void kernel_launch(void* const* d_in, const int* in_sizes, int n_in,
                              void* d_out, int out_size, void* d_ws, size_t ws_size,
                              hipStream_t stream) {
    const int*   index = (const int*)d_in[0];
    const float* value = (const float*)d_in[1];
    float*       out   = (float*)d_out;

    int n  = in_sizes[0];                 // 129
    int bd = in_sizes[1] / n;             // batch * dim = 8192
    const int dim = DIM;                  // 256 (per reference setup)
    int batch = bd / dim;                 // 32
    int m = out_size / bd;                // 4096

    dim3 grid(n - 1, (batch + 1) / 2);    // (128, 16) = 2048 blocks
    lpi_kernel<<<grid, 256, 0, stream>>>(index, value, out, n, m, batch);
}